// Round 4
// baseline (149.434 us; speedup 1.0000x reference)
//
#include <hip/hip_runtime.h>
#include <hip/hip_bf16.h>

#ifndef __has_builtin
#define __has_builtin(x) 0
#endif

__device__ __forceinline__ float fast_exp2(float x) {
#if __has_builtin(__builtin_amdgcn_exp2f)
  return __builtin_amdgcn_exp2f(x);
#else
  return exp2f(x);
#endif
}
__device__ __forceinline__ float fast_rcp(float x) {
#if __has_builtin(__builtin_amdgcn_rcpf)
  return __builtin_amdgcn_rcpf(x);
#else
  return 1.0f / x;
#endif
}

constexpr int Bsz = 8, QL = 128, KL = 512, DD = 256, UU = 256;
constexpr int QB = 1;                    // q rows per attn block (4 blocks/CU)
constexpr int PR = 8;                    // rows per proj block
constexpr int DT = 8;                    // d-chunk in proj pipeline
constexpr int UT = 16;                   // u-tile in attn pipeline (deep prefetch)
constexpr float NEG_INF = -1e6f;
constexpr float C2 = 2.885390081777927f; // 2*log2(e): exp2(C2*x) == exp(2x)

// ---------------------------------------------------------------------------
// Kernel 1: projections, pre-scaled by C2, register-double-buffered over d.
//   qp[b][q][u]  = C2 * sum_d query[b,q,d] * Wq[d,u]   ([B,Q,U])
//   kpT[b][u][k] = C2 * sum_d key[b,k,d]   * Wk[d,u]   ([B,U,K], transposed)
// (unchanged from round 3 to isolate the attn change)
// ---------------------------------------------------------------------------
__global__ __launch_bounds__(256) void proj_kernel(
    const float* __restrict__ query, const float* __restrict__ key,
    const float* __restrict__ Wq, const float* __restrict__ Wk,
    const int* __restrict__ valid_len,
    float* __restrict__ qp, float* __restrict__ kpT)
{
  const int u   = threadIdx.x;
  const int blk = blockIdx.x;
  constexpr int QBLKS = Bsz * QL / PR;   // 128
  const bool isQ = blk < QBLKS;
  const int  m0  = isQ ? blk * PR : (blk - QBLKS) * PR;

  int b = 0, k0 = 0;
  if (!isQ) {
    b = m0 / KL; k0 = m0 % KL;
    if (k0 >= valid_len[b]) return;      // masked rows never read by attn
  }
  const float* __restrict__ in = isQ ? query : key;
  const float* __restrict__ W  = isQ ? Wq : Wk;
  const float* r0 = in + (size_t)m0 * DD;

  float acc[PR];
#pragma unroll
  for (int r = 0; r < PR; ++r) acc[r] = 0.f;

  float  w_c[DT], w_n[DT];
  float4 r_c[PR][2], r_n[PR][2];

#pragma unroll
  for (int j = 0; j < DT; ++j) w_c[j] = W[j * UU + u];
#pragma unroll
  for (int r = 0; r < PR; ++r) {
    r_c[r][0] = *reinterpret_cast<const float4*>(r0 + r * DD);
    r_c[r][1] = *reinterpret_cast<const float4*>(r0 + r * DD + 4);
  }

  for (int d = 0; d < DD; d += DT) {
    const int dn = (d + DT < DD) ? d + DT : 0;
#pragma unroll
    for (int j = 0; j < DT; ++j) w_n[j] = W[(dn + j) * UU + u];
#pragma unroll
    for (int r = 0; r < PR; ++r) {
      r_n[r][0] = *reinterpret_cast<const float4*>(r0 + r * DD + dn);
      r_n[r][1] = *reinterpret_cast<const float4*>(r0 + r * DD + dn + 4);
    }
#pragma unroll
    for (int r = 0; r < PR; ++r) {
      float a = acc[r];
      a = fmaf(r_c[r][0].x, w_c[0], a);
      a = fmaf(r_c[r][0].y, w_c[1], a);
      a = fmaf(r_c[r][0].z, w_c[2], a);
      a = fmaf(r_c[r][0].w, w_c[3], a);
      a = fmaf(r_c[r][1].x, w_c[4], a);
      a = fmaf(r_c[r][1].y, w_c[5], a);
      a = fmaf(r_c[r][1].z, w_c[6], a);
      a = fmaf(r_c[r][1].w, w_c[7], a);
      acc[r] = a;
    }
#pragma unroll
    for (int j = 0; j < DT; ++j) w_c[j] = w_n[j];
#pragma unroll
    for (int r = 0; r < PR; ++r) { r_c[r][0] = r_n[r][0]; r_c[r][1] = r_n[r][1]; }
  }

  if (isQ) {
    float* o = qp + (size_t)m0 * UU + u;
#pragma unroll
    for (int r = 0; r < PR; ++r) o[r * UU] = acc[r] * C2;
  } else {
    float* o = kpT + ((size_t)b * UU + u) * KL + k0;
    *reinterpret_cast<float4*>(o) =
        make_float4(acc[0] * C2, acc[1] * C2, acc[2] * C2, acc[3] * C2);
    *reinterpret_cast<float4*>(o + 4) =
        make_float4(acc[4] * C2, acc[5] * C2, acc[6] * C2, acc[7] * C2);
  }
}

// ---------------------------------------------------------------------------
// Kernel 2: scores + masked softmax + attn@V. QB=1: block = (b, one q row);
// 1024 blocks -> 4 blocks/CU (launch_bounds(256,4)). Thread t owns
// k = {2t, 2t+1}; wave w skips the u-loop entirely when 128w >= vlen
// (blocked-k mask skip). Deep register prefetch: UT=16 float2 in flight.
// score[k] = Vsum - sum_u 2*v_w[u] * rcp(1 + exp2(qp[u] + kpT[u][k]))
// ---------------------------------------------------------------------------
__global__ __launch_bounds__(256, 4) void attn_kernel(
    const float* __restrict__ value, const int* __restrict__ valid_len,
    const float* __restrict__ v_w, const float* __restrict__ qp,
    const float* __restrict__ kpT, float* __restrict__ out)
{
  __shared__ __align__(16) float sc[KL];       // attn weights (2 KB)
  __shared__ float qp_s[UU];                   // 1 KB
  __shared__ float w2_s[UU];                   // 1 KB
  __shared__ float red_s[4];

  const int t    = threadIdx.x;
  const int lane = t & 63, wave = t >> 6;
  const int blk  = blockIdx.x;
  const int b    = blk & 7;                    // batch-interleaved mapping
  const int q0   = blk >> 3;                   // q row
  const int vlen = valid_len[b];

  // ---- stage qp row + 2*v_w into LDS; block-reduce Vsum = sum(v_w) ----
  const float vw = v_w[t];
  w2_s[t] = 2.0f * vw;
  qp_s[t] = qp[(size_t)(b * QL + q0) * UU + t];

  float s = vw;
#pragma unroll
  for (int off = 32; off >= 1; off >>= 1) s += __shfl_xor(s, off, 64);
  if (lane == 0) red_s[wave] = s;
  __syncthreads();
  const float vsum = red_s[0] + red_s[1] + red_s[2] + red_s[3];
  __syncthreads();

  // ---- score accumulation over u, deep software pipeline ----
  const int k2 = 2 * t;
  float acc0 = 0.f, acc1 = 0.f;

  if (k2 < vlen) {
    const float2* __restrict__ kp2 =
        reinterpret_cast<const float2*>(kpT + (size_t)b * UU * KL);
    float2 cur[UT], nxt[UT];
#pragma unroll
    for (int j = 0; j < UT; ++j) cur[j] = kp2[j * (KL / 2) + t];

    for (int u0 = 0; u0 < UU; u0 += UT) {
      const int un = (u0 + UT < UU) ? u0 + UT : 0;   // clamped dummy on last
#pragma unroll
      for (int j = 0; j < UT; ++j) nxt[j] = kp2[(un + j) * (KL / 2) + t];
#pragma unroll
      for (int j = 0; j < UT; ++j) {
        const float w2 = w2_s[u0 + j];
        const float qv = qp_s[u0 + j];
        const float e0 = fast_exp2(qv + cur[j].x);  // = exp(2x), pre-scaled
        const float e1 = fast_exp2(qv + cur[j].y);
        const float r0 = fast_rcp(1.0f + e0);       // tanh(x) = 1 - 2*r
        const float r1 = fast_rcp(1.0f + e1);
        acc0 = fmaf(w2, r0, acc0);
        acc1 = fmaf(w2, r1, acc1);
      }
#pragma unroll
      for (int j = 0; j < UT; ++j) cur[j] = nxt[j];
    }
  }

  // ---- mask + softmax over k ----
  float sr0 = (k2     < vlen) ? (vsum - acc0) : NEG_INF;
  float sr1 = (k2 + 1 < vlen) ? (vsum - acc1) : NEG_INF;
  float lmax = fmaxf(sr0, sr1);
#pragma unroll
  for (int off = 32; off >= 1; off >>= 1)
    lmax = fmaxf(lmax, __shfl_xor(lmax, off, 64));
  if (lane == 0) red_s[wave] = lmax;
  __syncthreads();
  const float mq = fmaxf(fmaxf(red_s[0], red_s[1]), fmaxf(red_s[2], red_s[3]));
  __syncthreads();

  const float ex0 = __expf(sr0 - mq);    // masked -> 0, matches ref
  const float ex1 = __expf(sr1 - mq);
  float lsum = ex0 + ex1;
#pragma unroll
  for (int off = 32; off >= 1; off >>= 1) lsum += __shfl_xor(lsum, off, 64);
  if (lane == 0) red_s[wave] = lsum;
  __syncthreads();
  const float tot = red_s[0] + red_s[1] + red_s[2] + red_s[3];
  const float inv = fast_rcp(tot);       // tot >= 1 (max term contributes 1)
  sc[k2]     = ex0 * inv;
  sc[k2 + 1] = ex1 * inv;
  __syncthreads();

  // ---- out[b,q,d] = sum_{k<vlen} attn[k]*value[b,k,d]; thread = d ------
  const int kmax = (vlen + 3) & ~3;      // sc beyond vlen is exactly 0
  const float* __restrict__ vb = value + (size_t)b * KL * DD;
  float ov = 0.f;

  float v_c[4], v_n[4];
#pragma unroll
  for (int j = 0; j < 4; ++j) v_c[j] = vb[j * DD + t];
  for (int k = 0; k < kmax; k += 4) {
    const int kn = (k + 4 < kmax) ? k + 4 : 0;
#pragma unroll
    for (int j = 0; j < 4; ++j) v_n[j] = vb[(kn + j) * DD + t];
    const float4 a = *reinterpret_cast<const float4*>(&sc[k]);
    ov = fmaf(a.x, v_c[0], fmaf(a.y, v_c[1],
          fmaf(a.z, v_c[2], fmaf(a.w, v_c[3], ov))));
#pragma unroll
    for (int j = 0; j < 4; ++j) v_c[j] = v_n[j];
  }
  out[(size_t)(b * QL + q0) * DD + t] = ov;
}

extern "C" void kernel_launch(void* const* d_in, const int* in_sizes, int n_in,
                              void* d_out, int out_size, void* d_ws, size_t ws_size,
                              hipStream_t stream) {
  const float* query     = (const float*)d_in[0];
  const float* key       = (const float*)d_in[1];
  const float* value     = (const float*)d_in[2];
  const int*   valid_len = (const int*)d_in[3];
  const float* Wq        = (const float*)d_in[4];
  const float* Wk        = (const float*)d_in[5];
  const float* v_w       = (const float*)d_in[6];
  float* out = (float*)d_out;

  float* qp  = (float*)d_ws;                       // B*QL*UU floats (1 MB)
  float* kpT = qp + (size_t)Bsz * QL * UU;         // B*UU*KL floats (4 MB)

  const int proj_blocks = (Bsz * QL + Bsz * KL) / PR;   // 128 + 512 = 640
  proj_kernel<<<proj_blocks, 256, 0, stream>>>(query, key, Wq, Wk, valid_len, qp, kpT);

  const int attn_blocks = Bsz * QL / QB;                // 1024
  attn_kernel<<<attn_blocks, 256, 0, stream>>>(value, valid_len, v_w, qp, kpT, out);
}

// Round 5
// 144.803 us; speedup vs baseline: 1.0320x; 1.0320x over previous
//
#include <hip/hip_runtime.h>
#include <hip/hip_bf16.h>

#ifndef __has_builtin
#define __has_builtin(x) 0
#endif

__device__ __forceinline__ float fast_exp2(float x) {
#if __has_builtin(__builtin_amdgcn_exp2f)
  return __builtin_amdgcn_exp2f(x);
#else
  return exp2f(x);
#endif
}
__device__ __forceinline__ float fast_rcp(float x) {
#if __has_builtin(__builtin_amdgcn_rcpf)
  return __builtin_amdgcn_rcpf(x);
#else
  return 1.0f / x;
#endif
}

constexpr int Bsz = 8, QL = 128, KL = 512, DD = 256, UU = 256;
constexpr int PR = 8;                    // rows per proj block
constexpr int DT = 8;                    // d-chunk in proj pipeline
constexpr int SQB = 8;                   // q rows per scores block
constexpr int SKB = 128;                 // k cols per scores block
constexpr int SUT = 8;                   // u-tile (LDS double buffer)
constexpr float NEG_INF = -1e6f;
constexpr float C2 = 2.885390081777927f; // 2*log2(e): exp2(C2*x) == exp(2x)

// ---------------------------------------------------------------------------
// Kernel 1: projections, pre-scaled by C2, BOTH outputs transposed:
//   qpT[b][u][q] (row 128), kpT[b][u][k] (row 512).
// thread = u; 8 rows/block; W coalesced + prefetched; fully-masked key
// blocks exit early (attn never reads masked kpT columns).
// ---------------------------------------------------------------------------
__global__ __launch_bounds__(256) void proj_kernel(
    const float* __restrict__ query, const float* __restrict__ key,
    const float* __restrict__ Wq, const float* __restrict__ Wk,
    const int* __restrict__ valid_len,
    float* __restrict__ qpT, float* __restrict__ kpT)
{
  const int u   = threadIdx.x;
  const int blk = blockIdx.x;
  constexpr int QBLKS = Bsz * QL / PR;   // 128
  const bool isQ = blk < QBLKS;
  const int  m0  = isQ ? blk * PR : (blk - QBLKS) * PR;

  int b, r0i;
  if (isQ) { b = m0 / QL; r0i = m0 % QL; }
  else     { b = m0 / KL; r0i = m0 % KL;
             if (r0i >= valid_len[b]) return; }
  const float* __restrict__ in = isQ ? query : key;
  const float* __restrict__ W  = isQ ? Wq : Wk;
  const float* r0 = in + (size_t)m0 * DD;

  float acc[PR];
#pragma unroll
  for (int r = 0; r < PR; ++r) acc[r] = 0.f;

  float  w_c[DT], w_n[DT];
  float4 r_c[PR][2], r_n[PR][2];

#pragma unroll
  for (int j = 0; j < DT; ++j) w_c[j] = W[j * UU + u];
#pragma unroll
  for (int r = 0; r < PR; ++r) {
    r_c[r][0] = *reinterpret_cast<const float4*>(r0 + r * DD);
    r_c[r][1] = *reinterpret_cast<const float4*>(r0 + r * DD + 4);
  }

  for (int d = 0; d < DD; d += DT) {
    const int dn = (d + DT < DD) ? d + DT : 0;
#pragma unroll
    for (int j = 0; j < DT; ++j) w_n[j] = W[(dn + j) * UU + u];
#pragma unroll
    for (int r = 0; r < PR; ++r) {
      r_n[r][0] = *reinterpret_cast<const float4*>(r0 + r * DD + dn);
      r_n[r][1] = *reinterpret_cast<const float4*>(r0 + r * DD + dn + 4);
    }
#pragma unroll
    for (int r = 0; r < PR; ++r) {
      float a = acc[r];
      a = fmaf(r_c[r][0].x, w_c[0], a);
      a = fmaf(r_c[r][0].y, w_c[1], a);
      a = fmaf(r_c[r][0].z, w_c[2], a);
      a = fmaf(r_c[r][0].w, w_c[3], a);
      a = fmaf(r_c[r][1].x, w_c[4], a);
      a = fmaf(r_c[r][1].y, w_c[5], a);
      a = fmaf(r_c[r][1].z, w_c[6], a);
      a = fmaf(r_c[r][1].w, w_c[7], a);
      acc[r] = a;
    }
#pragma unroll
    for (int j = 0; j < DT; ++j) w_c[j] = w_n[j];
#pragma unroll
    for (int r = 0; r < PR; ++r) { r_c[r][0] = r_n[r][0]; r_c[r][1] = r_n[r][1]; }
  }

  // transposed store: row u, 8 consecutive columns
  float* o = (isQ ? qpT + ((size_t)b * UU + u) * QL + r0i
                  : kpT + ((size_t)b * UU + u) * KL + r0i);
  *reinterpret_cast<float4*>(o) =
      make_float4(acc[0] * C2, acc[1] * C2, acc[2] * C2, acc[3] * C2);
  *reinterpret_cast<float4*>(o + 4) =
      make_float4(acc[4] * C2, acc[5] * C2, acc[6] * C2, acc[7] * C2);
}

// ---------------------------------------------------------------------------
// Kernel 2: scores tile (b, 8q, 128k). 512 blocks; 256 threads.
// Wave w owns q rows {q0+2w, q0+2w+1}; lane l owns k {k0+2l, k0+2l+1}.
// kpT tile (8u x 128k) LDS-double-buffered; qpT tile (256u x 8q) LDS-resident.
// sc[b][q][k] = -sum_u 2*v_w[u]*rcp(1+exp2(qp+kp))   (softmax shift-invariant:
// the constant sum(v_w) term is dropped). Masked k -> NEG_INF.
// Blocks with k0 >= vlen exit (kernel 3 substitutes NEG_INF itself).
// ---------------------------------------------------------------------------
__global__ __launch_bounds__(256) void scores_kernel(
    const int* __restrict__ valid_len, const float* __restrict__ v_w,
    const float* __restrict__ qpT, const float* __restrict__ kpT,
    float* __restrict__ sc)
{
  __shared__ float qp_s[UU][SQB];                       // 8 KB  [u][qoff]
  __shared__ float w2_s[UU];                            // 1 KB
  __shared__ __align__(16) float kp_s[2][SUT][SKB];     // 8 KB

  const int t = threadIdx.x;
  const int l = t & 63, w = t >> 6;
  const int blk = blockIdx.x;
  const int b  = blk & 7;
  const int qt = (blk >> 3) & 15;
  const int kt = blk >> 7;
  const int q0 = qt * SQB;
  const int k0 = kt * SKB;
  const int vlen = valid_len[b];
  if (k0 >= vlen) return;                // whole tile masked

  // stage 2*v_w and the qpT tile [256u][8q]
  w2_s[t] = 2.0f * v_w[t];
  {
    const float* qrow = qpT + ((size_t)b * UU + t) * QL + q0;  // u = t
    const float4 qa = *reinterpret_cast<const float4*>(qrow);
    const float4 qb = *reinterpret_cast<const float4*>(qrow + 4);
    *reinterpret_cast<float4*>(&qp_s[t][0]) = qa;
    *reinterpret_cast<float4*>(&qp_s[t][4]) = qb;
  }

  // kpT staging map: thread t -> u_r = t>>5, k4 = (t&31)*4 (float4)
  const int u_r = t >> 5, kk = (t & 31) * 4;
  const float* kbase = kpT + (size_t)b * UU * KL + k0 + (size_t)u_r * KL + kk;
  float4 kreg = *reinterpret_cast<const float4*>(kbase);   // tile 0

  float a00 = 0.f, a01 = 0.f, a10 = 0.f, a11 = 0.f;        // [q 2][k 2]

  for (int u0 = 0; u0 < UU; u0 += SUT) {
    const int buf = (u0 >> 3) & 1;
    *reinterpret_cast<float4*>(&kp_s[buf][u_r][kk]) = kreg;
    __syncthreads();
    if (u0 + SUT < UU)
      kreg = *reinterpret_cast<const float4*>(kbase + (size_t)(u0 + SUT) * KL);
#pragma unroll
    for (int j = 0; j < SUT; ++j) {
      const int u = u0 + j;
      const float2 qv = *reinterpret_cast<const float2*>(&qp_s[u][2 * w]);
      const float  w2 = w2_s[u];
      const float2 kv = *reinterpret_cast<const float2*>(&kp_s[buf][j][2 * l]);
      const float e00 = fast_exp2(qv.x + kv.x);
      const float e01 = fast_exp2(qv.x + kv.y);
      const float e10 = fast_exp2(qv.y + kv.x);
      const float e11 = fast_exp2(qv.y + kv.y);
      a00 = fmaf(w2, fast_rcp(1.0f + e00), a00);
      a01 = fmaf(w2, fast_rcp(1.0f + e01), a01);
      a10 = fmaf(w2, fast_rcp(1.0f + e10), a10);
      a11 = fmaf(w2, fast_rcp(1.0f + e11), a11);
    }
  }

  // write scores (masked -> NEG_INF)
  const int kg = k0 + 2 * l;
  const bool m0ok = kg < vlen, m1ok = (kg + 1) < vlen;
  const int r0 = q0 + 2 * w;
  float2 o0, o1;
  o0.x = m0ok ? -a00 : NEG_INF;  o0.y = m1ok ? -a01 : NEG_INF;
  o1.x = m0ok ? -a10 : NEG_INF;  o1.y = m1ok ? -a11 : NEG_INF;
  *reinterpret_cast<float2*>(sc + ((size_t)b * QL + r0) * KL + kg)     = o0;
  *reinterpret_cast<float2*>(sc + ((size_t)b * QL + r0 + 1) * KL + kg) = o1;
}

// ---------------------------------------------------------------------------
// Kernel 3: masked softmax over k + attn@value for tile (b, 8q, 128d).
// 256 blocks; 256 threads = [d-lane 128][q-group 2]. Wave w softmaxes rows
// {2w, 2w+1} (full row in its lanes, shuffle-reduced). PV: 16-k chunks,
// value prefetched one chunk ahead; p_s reads are wave-uniform broadcasts.
// ---------------------------------------------------------------------------
__global__ __launch_bounds__(256) void softmax_pv_kernel(
    const float* __restrict__ value, const int* __restrict__ valid_len,
    const float* __restrict__ sc, float* __restrict__ out)
{
  __shared__ __align__(16) float p_s[SQB][KL];   // 16 KB attn weights

  const int t = threadIdx.x;
  const int l = t & 63, w = t >> 6;
  const int blk = blockIdx.x;
  const int b  = blk & 7;
  const int qt = (blk >> 3) & 15;
  const int dh = blk >> 7;
  const int q0 = qt * SQB;
  const int d0 = dh * 128;
  const int vlen = valid_len[b];

  // ---- load + masked softmax; wave w owns rows 2w, 2w+1 ----
#pragma unroll
  for (int r = 0; r < 2; ++r) {
    const int row = 2 * w + r;
    const float* srow = sc + ((size_t)b * QL + q0 + row) * KL;
    const int kb = l * 8;
    float v[8];
#pragma unroll
    for (int j = 0; j < 8; ++j)
      v[j] = (kb + j < vlen) ? srow[kb + j] : NEG_INF;
    float m = v[0];
#pragma unroll
    for (int j = 1; j < 8; ++j) m = fmaxf(m, v[j]);
#pragma unroll
    for (int off = 32; off >= 1; off >>= 1) m = fmaxf(m, __shfl_xor(m, off, 64));
    float s = 0.f;
#pragma unroll
    for (int j = 0; j < 8; ++j) { v[j] = __expf(v[j] - m); s += v[j]; }
#pragma unroll
    for (int off = 32; off >= 1; off >>= 1) s += __shfl_xor(s, off, 64);
    const float inv = fast_rcp(s);       // s >= 1 (max term contributes 1)
#pragma unroll
    for (int j = 0; j < 8; ++j) p_s[row][kb + j] = v[j] * inv;
  }
  __syncthreads();

  // ---- PV: thread = (d-lane, q-group of 4 rows) ----
  const int dl = t & 127, qg = t >> 7;
  const float* __restrict__ vb = value + (size_t)b * KL * DD + d0 + dl;
  float acc[4] = {0.f, 0.f, 0.f, 0.f};
  const int kmax = (vlen + 15) & ~15;    // p_s beyond vlen is exactly 0

  float vc[16], vn[16];
#pragma unroll
  for (int j = 0; j < 16; ++j) vc[j] = vb[(size_t)j * DD];
  for (int k = 0; k < kmax; k += 16) {
    const int kn = (k + 16 < kmax) ? k + 16 : 0;
#pragma unroll
    for (int j = 0; j < 16; ++j) vn[j] = vb[(size_t)(kn + j) * DD];
#pragma unroll
    for (int g = 0; g < 4; ++g) {
#pragma unroll
      for (int q = 0; q < 4; ++q) {
        const float4 a = *reinterpret_cast<const float4*>(&p_s[qg * 4 + q][k + 4 * g]);
        acc[q] = fmaf(a.x, vc[4 * g + 0], fmaf(a.y, vc[4 * g + 1],
                 fmaf(a.z, vc[4 * g + 2], fmaf(a.w, vc[4 * g + 3], acc[q]))));
      }
    }
#pragma unroll
    for (int j = 0; j < 16; ++j) vc[j] = vn[j];
  }
#pragma unroll
  for (int q = 0; q < 4; ++q)
    out[((size_t)b * QL + q0 + qg * 4 + q) * DD + d0 + dl] = acc[q];
}

extern "C" void kernel_launch(void* const* d_in, const int* in_sizes, int n_in,
                              void* d_out, int out_size, void* d_ws, size_t ws_size,
                              hipStream_t stream) {
  const float* query     = (const float*)d_in[0];
  const float* key       = (const float*)d_in[1];
  const float* value     = (const float*)d_in[2];
  const int*   valid_len = (const int*)d_in[3];
  const float* Wq        = (const float*)d_in[4];
  const float* Wk        = (const float*)d_in[5];
  const float* v_w       = (const float*)d_in[6];
  float* out = (float*)d_out;

  float* qpT = (float*)d_ws;                        // B*U*QL floats (1 MB)
  float* kpT = qpT + (size_t)Bsz * UU * QL;         // B*U*KL floats (4 MB)
  float* sc  = kpT + (size_t)Bsz * UU * KL;         // B*QL*KL floats (2 MB)

  const int proj_blocks = (Bsz * QL + Bsz * KL) / PR;   // 640
  proj_kernel<<<proj_blocks, 256, 0, stream>>>(query, key, Wq, Wk, valid_len,
                                               qpT, kpT);

  const int score_blocks = Bsz * (QL / SQB) * (KL / SKB);  // 8*16*4 = 512
  scores_kernel<<<score_blocks, 256, 0, stream>>>(valid_len, v_w, qpT, kpT, sc);

  const int pv_blocks = Bsz * (QL / SQB) * (DD / 128);     // 8*16*2 = 256
  softmax_pv_kernel<<<pv_blocks, 256, 0, stream>>>(value, valid_len, sc, out);
}